// Round 4
// baseline (240.997 us; speedup 1.0000x reference)
//
#include <hip/hip_runtime.h>

// KAN layer forward, MI355X. Inputs AND outputs are float32 buffers
// (established R3: f32 template path ran -> finite; bf16 output writes read
// back as f32 gave error ~= max|y_out| -> output buffer is f32).
// Input values are bf16-rounded f32 (harness casts through bf16), which is
// irrelevant to the kernel.
//
// Outputs (flat concat, f32): y_out[1024,128], preacts[1024,128,128],
// postacts[1024,128,128], postspline[1024,128,128].
//
// One block = GB(4) batch rows x all 128 j. Phase 1: 512 (g,i) basis
// computations (exact Cox-de Boor on the extended grid, matching the
// reference's extend_grid + b_batch) into LDS. Phase 2: wave w owns
// j in [32w,32w+32); per j the coef row + scales are loaded once and
// reused across the 4 batch rows; lane <-> i (i=lane, i=lane+64);
// wave-shuffle reduction for y_out.

#define IN_DIM  128
#define OUT_DIM 128
#define NUMG    5
#define KORD    3
#define NB      8          // NUMG + KORD basis functions
#define SIZE    (IN_DIM * OUT_DIM)
#define BATCH   1024
#define GB      4          // batch rows per block

__device__ __forceinline__ float dotf(float4 qa, float4 qb, float4 a, float4 b) {
    float r = qa.x * a.x;
    r = fmaf(qa.y, a.y, r); r = fmaf(qa.z, a.z, r); r = fmaf(qa.w, a.w, r);
    r = fmaf(qb.x, b.x, r); r = fmaf(qb.y, b.y, r);
    r = fmaf(qb.z, b.z, r); r = fmaf(qb.w, b.w, r);
    return r;
}

struct Smem {
    float B[GB][IN_DIM][NB];
    float silu[GB][IN_DIM];
    float xv[GB][IN_DIM];
};

__global__ __launch_bounds__(256) void kan_fused(
    const float* __restrict__ x,
    const float* __restrict__ grid,
    const float* __restrict__ coef,
    const float* __restrict__ scale_base,
    const float* __restrict__ scale_sp,
    const float* __restrict__ mask,
    float* __restrict__ out)
{
    __shared__ Smem sm;
    const int tid = threadIdx.x;
    const int b0  = blockIdx.x * GB;

    // ---- Phase 1: basis + silu for 512 (g,i) pairs, 2 per thread ----
    #pragma unroll
    for (int rep = 0; rep < 2; ++rep) {
        const int idx = rep * 256 + tid;          // 0..511
        const int g = idx >> 7, i = idx & 127;
        const float xv = x[(b0 + g) * IN_DIM + i];

        float gr[NUMG + 1];
        #pragma unroll
        for (int r = 0; r <= NUMG; ++r) gr[r] = grid[i * (NUMG + 1) + r];

        const float h = (gr[NUMG] - gr[0]) * (1.0f / NUMG);
        float t[NUMG + 1 + 2 * KORD];             // 12 knots
        // sequential extension, matching extend_grid's repeated +-h
        t[2] = gr[0] - h; t[1] = t[2] - h; t[0] = t[1] - h;
        #pragma unroll
        for (int r = 0; r <= NUMG; ++r) t[KORD + r] = gr[r];
        t[9] = gr[NUMG] + h; t[10] = t[9] + h; t[11] = t[10] + h;

        float B[NUMG + 2 * KORD];                 // 11 -> 10 -> 9 -> 8
        #pragma unroll
        for (int m = 0; m < NUMG + 2 * KORD; ++m)
            B[m] = (xv >= t[m] && xv < t[m + 1]) ? 1.0f : 0.0f;
        #pragma unroll
        for (int p = 1; p <= KORD; ++p) {
            #pragma unroll
            for (int m = 0; m < NUMG + 2 * KORD - p; ++m) {
                B[m] = (xv - t[m]) / (t[m + p] - t[m]) * B[m]
                     + (t[m + p + 1] - xv) / (t[m + p + 1] - t[m + 1]) * B[m + 1];
            }
        }

        #pragma unroll
        for (int m = 0; m < NB; ++m) sm.B[g][i][m] = B[m];
        sm.silu[g][i] = xv / (1.0f + __expf(-xv));
        sm.xv[g][i]   = xv;
    }
    __syncthreads();

    // ---- Phase 2: wave w owns j in [32w, 32w+32); lane <-> i, i+64 ----
    const int lane = tid & 63;
    const int w    = tid >> 6;

    float4 A0[GB], A1[GB], C0[GB], C1[GB];
    float sl0[GB], sl1[GB], px0[GB], px1[GB];
    #pragma unroll
    for (int g = 0; g < GB; ++g) {
        A0[g] = *(const float4*)&sm.B[g][lane][0];
        A1[g] = *(const float4*)&sm.B[g][lane][4];
        C0[g] = *(const float4*)&sm.B[g][lane + 64][0];
        C1[g] = *(const float4*)&sm.B[g][lane + 64][4];
        sl0[g] = sm.silu[g][lane];
        sl1[g] = sm.silu[g][lane + 64];
        px0[g] = sm.xv[g][lane];
        px1[g] = sm.xv[g][lane + 64];
    }

    float* out_y   = out;
    float* out_pre = out + BATCH * OUT_DIM;
    float* out_act = out_pre + (size_t)BATCH * SIZE;
    float* out_spl = out_act + (size_t)BATCH * SIZE;

    #pragma unroll 2
    for (int jj = 0; jj < 32; ++jj) {
        const int j  = w * 32 + jj;
        const int s0 = j * IN_DIM + lane;
        const int s1 = s0 + 64;

        const float4* cp = (const float4*)coef;
        const float4 q0a = cp[2 * s0], q0b = cp[2 * s0 + 1];
        const float4 q1a = cp[2 * s1], q1b = cp[2 * s1 + 1];
        const float m0   = mask[s0],       m1   = mask[s1];
        const float sbv0 = scale_base[s0], sbv1 = scale_base[s1];
        const float ssv0 = scale_sp[s0],   ssv1 = scale_sp[s1];

        #pragma unroll
        for (int g = 0; g < GB; ++g) {
            const float sp0 = dotf(q0a, q0b, A0[g], A1[g]);
            const float sp1 = dotf(q1a, q1b, C0[g], C1[g]);
            const float y0  = m0 * (sbv0 * sl0[g] + ssv0 * sp0);
            const float y1  = m1 * (sbv1 * sl1[g] + ssv1 * sp1);

            const size_t e0 = (size_t)(b0 + g) * SIZE + (size_t)s0;
            out_pre[e0]      = px0[g];
            out_pre[e0 + 64] = px1[g];
            out_act[e0]      = y0;
            out_act[e0 + 64] = y1;
            out_spl[e0]      = sp0;
            out_spl[e0 + 64] = sp1;

            float acc = y0 + y1;
            #pragma unroll
            for (int off = 32; off > 0; off >>= 1)
                acc += __shfl_down(acc, off, 64);
            if (lane == 0) out_y[(b0 + g) * OUT_DIM + j] = acc;
        }
    }
}

extern "C" void kernel_launch(void* const* d_in, const int* in_sizes, int n_in,
                              void* d_out, int out_size, void* d_ws, size_t ws_size,
                              hipStream_t stream)
{
    hipLaunchKernelGGL(kan_fused, dim3(BATCH / GB), dim3(256), 0, stream,
                       (const float*)d_in[0], (const float*)d_in[1],
                       (const float*)d_in[2], (const float*)d_in[3],
                       (const float*)d_in[4], (const float*)d_in[5],
                       (float*)d_out);
}

// Round 5
// 225.121 us; speedup vs baseline: 1.0705x; 1.0705x over previous
//
#include <hip/hip_runtime.h>

// KAN layer forward, MI355X. Inputs AND outputs are float32 buffers.
// Outputs (flat concat, f32): y_out[1024,128], preacts[1024,128,128],
// postacts[1024,128,128], postspline[1024,128,128].
//
// R4 -> R5: the 256-block version was latency-bound (1 block/CU = 1 wave/SIMD,
// zero hiding; 241 us vs 32 us write floor). Now: 2048 blocks (one per
// (batch row, j-half)), 4 waves/block, wave handles 16 j -> ~8 blocks/CU,
// full occupancy. Coef rows re-read per block but L2-resident (0.5 MB).
//
// Phase 1: threads 0..127 compute the 8-wide B-spline basis (exact Cox-de
// Boor on the extended grid, matching extend_grid + b_batch) + silu into LDS.
// Phase 2: lane <-> i (i=lane, i=lane+64); per j: coalesced float4 coef
// loads, f32 math, scalar coalesced stores, wave-shuffle y_out reduction.

#define IN_DIM  128
#define OUT_DIM 128
#define NUMG    5
#define KORD    3
#define NB      8          // NUMG + KORD basis functions
#define SIZE    (IN_DIM * OUT_DIM)
#define BATCH   1024

__device__ __forceinline__ float dotf(float4 qa, float4 qb, float4 a, float4 b) {
    float r = qa.x * a.x;
    r = fmaf(qa.y, a.y, r); r = fmaf(qa.z, a.z, r); r = fmaf(qa.w, a.w, r);
    r = fmaf(qb.x, b.x, r); r = fmaf(qb.y, b.y, r);
    r = fmaf(qb.z, b.z, r); r = fmaf(qb.w, b.w, r);
    return r;
}

__global__ __launch_bounds__(256) void kan_fused(
    const float* __restrict__ x,
    const float* __restrict__ grid,
    const float* __restrict__ coef,
    const float* __restrict__ scale_base,
    const float* __restrict__ scale_sp,
    const float* __restrict__ mask,
    float* __restrict__ out)
{
    __shared__ float sB[IN_DIM][NB];
    __shared__ float sSilu[IN_DIM];
    __shared__ float sXv[IN_DIM];

    const int tid  = threadIdx.x;
    const int b    = blockIdx.x >> 1;          // batch row
    const int half = blockIdx.x & 1;           // j half: [0,64) or [64,128)

    // ---- Phase 1: basis + silu for i = tid (threads 0..127) ----
    if (tid < IN_DIM) {
        const int i = tid;
        const float xv = x[b * IN_DIM + i];

        float gr[NUMG + 1];
        #pragma unroll
        for (int r = 0; r <= NUMG; ++r) gr[r] = grid[i * (NUMG + 1) + r];

        const float h = (gr[NUMG] - gr[0]) * (1.0f / NUMG);
        float t[NUMG + 1 + 2 * KORD];             // 12 knots
        // sequential extension, matching extend_grid's repeated +-h
        t[2] = gr[0] - h; t[1] = t[2] - h; t[0] = t[1] - h;
        #pragma unroll
        for (int r = 0; r <= NUMG; ++r) t[KORD + r] = gr[r];
        t[9] = gr[NUMG] + h; t[10] = t[9] + h; t[11] = t[10] + h;

        float B[NUMG + 2 * KORD];                 // 11 -> 10 -> 9 -> 8
        #pragma unroll
        for (int m = 0; m < NUMG + 2 * KORD; ++m)
            B[m] = (xv >= t[m] && xv < t[m + 1]) ? 1.0f : 0.0f;
        #pragma unroll
        for (int p = 1; p <= KORD; ++p) {
            #pragma unroll
            for (int m = 0; m < NUMG + 2 * KORD - p; ++m) {
                B[m] = (xv - t[m]) / (t[m + p] - t[m]) * B[m]
                     + (t[m + p + 1] - xv) / (t[m + p + 1] - t[m + 1]) * B[m + 1];
            }
        }

        #pragma unroll
        for (int m = 0; m < NB; ++m) sB[i][m] = B[m];
        sSilu[i] = xv / (1.0f + __expf(-xv));
        sXv[i]   = xv;
    }
    __syncthreads();

    // ---- Phase 2: wave w owns j in half*64 + [16w, 16w+16) ----
    const int lane = tid & 63;
    const int w    = tid >> 6;

    const float4 a0 = *(const float4*)&sB[lane][0];
    const float4 a1 = *(const float4*)&sB[lane][4];
    const float4 c0 = *(const float4*)&sB[lane + 64][0];
    const float4 c1 = *(const float4*)&sB[lane + 64][4];
    const float sl0 = sSilu[lane],  sl1 = sSilu[lane + 64];
    const float px0 = sXv[lane],    px1 = sXv[lane + 64];

    float* out_y   = out;
    float* out_pre = out + BATCH * OUT_DIM;
    float* out_act = out_pre + (size_t)BATCH * SIZE;
    float* out_spl = out_act + (size_t)BATCH * SIZE;

    #pragma unroll 4
    for (int jj = 0; jj < 16; ++jj) {
        const int j  = half * 64 + w * 16 + jj;
        const int s0 = j * IN_DIM + lane;
        const int s1 = s0 + 64;

        const float4* cp = (const float4*)coef;
        const float4 q0a = cp[2 * s0], q0b = cp[2 * s0 + 1];
        const float4 q1a = cp[2 * s1], q1b = cp[2 * s1 + 1];
        const float m0   = mask[s0],       m1   = mask[s1];
        const float sbv0 = scale_base[s0], sbv1 = scale_base[s1];
        const float ssv0 = scale_sp[s0],   ssv1 = scale_sp[s1];

        const float sp0 = dotf(q0a, q0b, a0, a1);
        const float sp1 = dotf(q1a, q1b, c0, c1);
        const float y0  = m0 * (sbv0 * sl0 + ssv0 * sp0);
        const float y1  = m1 * (sbv1 * sl1 + ssv1 * sp1);

        const size_t e0 = (size_t)b * SIZE + (size_t)s0;
        out_pre[e0]      = px0;
        out_pre[e0 + 64] = px1;
        out_act[e0]      = y0;
        out_act[e0 + 64] = y1;
        out_spl[e0]      = sp0;
        out_spl[e0 + 64] = sp1;

        float acc = y0 + y1;
        #pragma unroll
        for (int off = 32; off > 0; off >>= 1)
            acc += __shfl_down(acc, off, 64);
        if (lane == 0) out_y[b * OUT_DIM + j] = acc;
    }
}

extern "C" void kernel_launch(void* const* d_in, const int* in_sizes, int n_in,
                              void* d_out, int out_size, void* d_ws, size_t ws_size,
                              hipStream_t stream)
{
    hipLaunchKernelGGL(kan_fused, dim3(BATCH * 2), dim3(256), 0, stream,
                       (const float*)d_in[0], (const float*)d_in[1],
                       (const float*)d_in[2], (const float*)d_in[3],
                       (const float*)d_in[4], (const float*)d_in[5],
                       (float*)d_out);
}